// Round 5
// baseline (1196.391 us; speedup 1.0000x reference)
//
#include <hip/hip_runtime.h>
#include <hip/hip_bf16.h>

#define MDIM 64

typedef __attribute__((ext_vector_type(8))) short short8;
typedef __attribute__((ext_vector_type(4))) float f32x4;

__device__ __forceinline__ unsigned short bf16_of(float x) {
  __hip_bfloat16 b = __float2bfloat16(x);   // RNE
  return *reinterpret_cast<unsigned short*>(&b);
}
__device__ __forceinline__ float f32_of(unsigned short h) {
  return __uint_as_float(((unsigned int)h) << 16);
}
__device__ __forceinline__ void split2(float x, short& h, short& l) {
  unsigned short hh = bf16_of(x);
  h = (short)hh;
  l = (short)bf16_of(x - f32_of(hh));
}

// ---------------- Kernel 1: partial Gram G = X^T X via bf16-split MFMA ----------------
// 256 thr = 4 waves; global wave gw owns disjoint 32-row chunks, accumulates a full
// 64x64 G-partial in 16 mfma_16x16x32 tiles, writes partials[gw]. No LDS, no SMEM.
// Fragment trick: G is operand-symmetric, so frag(b) (cols [16b,16b+16)) serves as
// both A and B; any internal k-permutation cancels (A,B share the slot map).
__global__ __launch_bounds__(256) void k_gram(const float* __restrict__ X,
                                              float* __restrict__ partials,
                                              int N, int cpw) {
  const int t = threadIdx.x;
  const int lane = t & 63;
  const int wave = t >> 6;
  const int gw = blockIdx.x * 4 + wave;     // 0..1023
  const int col = lane & 15;
  const int kg = lane >> 4;                 // k = kg*8 + e

  f32x4 acc[16];
#pragma unroll
  for (int i = 0; i < 16; ++i) acc[i] = (f32x4){0.f, 0.f, 0.f, 0.f};

  for (int c = 0; c < cpw; ++c) {
    long r0 = ((long)gw * cpw + c) * 32;
    if (r0 >= N) break;
    short8 fh[4], fl[4];
#pragma unroll
    for (int b = 0; b < 4; ++b) {
      const float* p = X + (r0 + kg * 8) * MDIM + b * 16 + col;
#pragma unroll
      for (int e = 0; e < 8; ++e) {
        long r = r0 + kg * 8 + e;
        float x = (r < N) ? p[e * MDIM] : 0.f;   // lanes 0-15: 64B contiguous
        short h, l;
        split2(x, h, l);
        fh[b][e] = h;
        fl[b][e] = l;
      }
    }
#pragma unroll
    for (int bi = 0; bi < 4; ++bi)
#pragma unroll
      for (int bj = 0; bj < 4; ++bj) {
        int idx = bi * 4 + bj;
        acc[idx] = __builtin_amdgcn_mfma_f32_16x16x32_bf16(fh[bi], fh[bj], acc[idx], 0, 0, 0);
        acc[idx] = __builtin_amdgcn_mfma_f32_16x16x32_bf16(fh[bi], fl[bj], acc[idx], 0, 0, 0);
        acc[idx] = __builtin_amdgcn_mfma_f32_16x16x32_bf16(fl[bi], fh[bj], acc[idx], 0, 0, 0);
      }
  }

  // C/D layout (verified m89/m91): col = lane&15, row = (lane>>4)*4 + reg
  float* p = partials + (long)gw * 4096;
#pragma unroll
  for (int bi = 0; bi < 4; ++bi)
#pragma unroll
    for (int bj = 0; bj < 4; ++bj)
#pragma unroll
      for (int q = 0; q < 4; ++q)
        p[(bi * 16 + kg * 4 + q) * MDIM + bj * 16 + col] = acc[bi * 4 + bj][q];
}

// ---------------- Kernel 2a/2b: two-stage reduce of partials -> G ----------------
__global__ __launch_bounds__(256) void k_reduce1(const float* __restrict__ partials,
                                                 float* __restrict__ P2, int nblk) {
  int g = blockIdx.x * 256 + threadIdx.x;  // 0..65535
  int e = g & 4095, s = g >> 12;           // 16 slices
  int p0 = (nblk * s) >> 4, p1 = (nblk * (s + 1)) >> 4;
  float sum = 0.f;
  for (int p = p0; p < p1; ++p) sum += partials[(long)p * 4096 + e];
  P2[g] = sum;
}

__global__ __launch_bounds__(256) void k_reduce2(const float* __restrict__ P2,
                                                 float* __restrict__ G) {
  int e = blockIdx.x * 256 + threadIdx.x;  // grid 16
  float sum = 0.f;
#pragma unroll
  for (int s = 0; s < 16; ++s) sum += P2[s * 4096 + e];
  G[e] = sum;
}

// ---------------- Kernel 3: register Cholesky + triangular inverse, 1 wave ----------
// Thread t holds row t of A in 64 VGPRs (all loops fully unrolled -> static indexing).
// Column broadcasts via __shfl with compile-const lane (v_readlane). Zero LDS.
// Emits Rinv = (L^-1)^T directly as bf16 hi/lo for the MFMA apply.
__global__ __launch_bounds__(64) void k_cholinv(const float* __restrict__ G,
                                                unsigned short* __restrict__ Rh,
                                                unsigned short* __restrict__ Rl) {
  const int t = threadIdx.x;
  float row[64];
#pragma unroll
  for (int j4 = 0; j4 < 16; ++j4)
    *reinterpret_cast<f32x4*>(&row[j4 * 4]) =
        *reinterpret_cast<const f32x4*>(G + t * MDIM + j4 * 4);

  float inv_own = 0.f;
#pragma unroll
  for (int k = 0; k < 64; ++k) {
    float dkk = __shfl(row[k], k, 64);
    float s = sqrtf(dkk);
    float inv = 1.f / s;
    float lk = row[k] * inv;        // L[t][k] (valid for t>=k; t<k lanes: unread junk)
    if (t == k) inv_own = inv;
    row[k] = lk;
#pragma unroll
    for (int j = k + 1; j < 64; ++j) {
      float ljk = __shfl(lk, j, 64);
      row[j] = fmaf(-lk, ljk, row[j]);   // symmetric rank-1 update
    }
  }

  // Thread t solves L y = e_t (forward substitution); y_i = Linv[i][t] = Rinv[t][i].
  float y[64];
#pragma unroll
  for (int i = 0; i < 64; ++i) y[i] = 0.f;
#pragma unroll
  for (int i = 0; i < 64; ++i) {
    float s = (t == i) ? 1.f : 0.f;
#pragma unroll
    for (int m = 0; m < i; ++m) {
      float lim = __shfl(row[m], i, 64);  // L[i][m], finalized at step m
      s = fmaf(-lim, y[m], s);
    }
    float invdi = __shfl(inv_own, i, 64);
    y[i] = s * invdi;                     // zero for i<t automatically
  }

#pragma unroll
  for (int j = 0; j < 64; ++j) {
    float v = y[j];
    unsigned short h = bf16_of(v);
    Rh[t * MDIM + j] = h;
    Rl[t * MDIM + j] = bf16_of(v - f32_of(h));
  }
}

// ---------------- Kernel 4: Q = X * Rinv via bf16-split MFMA -----------------------
// 4 waves/block; wave owns 16 contiguous 16-row tiles. Rinv hi/lo fragments hoisted
// into registers once per wave; X rows read once (float4); Q written coalesced.
__global__ __launch_bounds__(256) void k_apply(const float* __restrict__ X,
                                               const unsigned short* __restrict__ Rh,
                                               const unsigned short* __restrict__ Rl,
                                               float* __restrict__ Q, int N) {
  const int t = threadIdx.x;
  const int lane = t & 63;
  const int wave = t >> 6;
  const int col = lane & 15;
  const int kg = lane >> 4;

  // B-frags: B[k][j], j = jb*16+col, k = kc*32 + kg*8 + e
  short8 bh[4][2], bl[4][2];
#pragma unroll
  for (int jb = 0; jb < 4; ++jb)
#pragma unroll
    for (int kc = 0; kc < 2; ++kc)
#pragma unroll
      for (int e = 0; e < 8; ++e) {
        int k = kc * 32 + kg * 8 + e;
        bh[jb][kc][e] = (short)Rh[k * MDIM + jb * 16 + col];
        bl[jb][kc][e] = (short)Rl[k * MDIM + jb * 16 + col];
      }

  long base = ((long)blockIdx.x * 4 + wave) * 256;   // 16 tiles x 16 rows
#pragma unroll 1
  for (int i = 0; i < 16; ++i) {
    long r0 = base + i * 16;
    if (r0 >= N) break;
    long rr = r0 + col;
    if (rr > N - 1) rr = N - 1;
    const float* xp = X + rr * MDIM + kg * 8;

    short8 ah[2], al[2];
#pragma unroll
    for (int kc = 0; kc < 2; ++kc) {
      float xv[8];
      *reinterpret_cast<f32x4*>(&xv[0]) = *reinterpret_cast<const f32x4*>(xp + kc * 32);
      *reinterpret_cast<f32x4*>(&xv[4]) = *reinterpret_cast<const f32x4*>(xp + kc * 32 + 4);
#pragma unroll
      for (int e = 0; e < 8; ++e) {
        short h, l;
        split2(xv[e], h, l);
        ah[kc][e] = h;
        al[kc][e] = l;
      }
    }

    f32x4 q[4];
#pragma unroll
    for (int jb = 0; jb < 4; ++jb) q[jb] = (f32x4){0.f, 0.f, 0.f, 0.f};
#pragma unroll
    for (int jb = 0; jb < 4; ++jb)
#pragma unroll
      for (int kc = 0; kc < 2; ++kc) {
        q[jb] = __builtin_amdgcn_mfma_f32_16x16x32_bf16(ah[kc], bh[jb][kc], q[jb], 0, 0, 0);
        q[jb] = __builtin_amdgcn_mfma_f32_16x16x32_bf16(ah[kc], bl[jb][kc], q[jb], 0, 0, 0);
        q[jb] = __builtin_amdgcn_mfma_f32_16x16x32_bf16(al[kc], bh[jb][kc], q[jb], 0, 0, 0);
      }

    // C/D: col = lane&15, row = kg*4 + reg
#pragma unroll
    for (int jb = 0; jb < 4; ++jb)
#pragma unroll
      for (int qq = 0; qq < 4; ++qq) {
        long orow = r0 + kg * 4 + qq;
        if (orow < N) Q[orow * MDIM + jb * 16 + col] = q[jb][qq];
      }
  }
}

extern "C" void kernel_launch(void* const* d_in, const int* in_sizes, int n_in,
                              void* d_out, int out_size, void* d_ws, size_t ws_size,
                              hipStream_t stream) {
  const float* X = (const float*)d_in[0];
  float* Q = (float*)d_out;
  const int N = in_sizes[0] / MDIM;

  float* ws = (float*)d_ws;
  float* G = ws;                                   // 4096 f32
  float* P2 = ws + 4096;                           // 65536 f32
  unsigned short* Rh = (unsigned short*)(ws + 69632);  // 4096 bf16
  unsigned short* Rl = (unsigned short*)(ws + 71680);  // 4096 bf16
  float* partials = ws + 73728;                    // 1024 * 4096 f32

  const int nwave = 1024;                          // 256 blocks x 4 waves
  int chunks = (N + 31) / 32;
  int cpw = (chunks + nwave - 1) / nwave;

  k_gram<<<256, 256, 0, stream>>>(X, partials, N, cpw);
  k_reduce1<<<256, 256, 0, stream>>>(partials, P2, nwave);
  k_reduce2<<<16, 256, 0, stream>>>(P2, G);
  k_cholinv<<<1, 64, 0, stream>>>(G, Rh, Rl);
  k_apply<<<(int)((N + 1023) / 1024), 256, 0, stream>>>(X, Rh, Rl, Q, N);
}

// Round 7
// 597.062 us; speedup vs baseline: 2.0038x; 2.0038x over previous
//
#include <hip/hip_runtime.h>
#include <hip/hip_bf16.h>

#define MDIM 64

typedef __attribute__((ext_vector_type(8))) short short8;
typedef __attribute__((ext_vector_type(4))) float f32x4;

__device__ __forceinline__ unsigned short bf16_of(float x) {
  __hip_bfloat16 b = __float2bfloat16(x);   // RNE
  return *reinterpret_cast<unsigned short*>(&b);
}
__device__ __forceinline__ float f32_of(unsigned short h) {
  return __uint_as_float(((unsigned int)h) << 16);
}
__device__ __forceinline__ void split2(float x, short& h, short& l) {
  unsigned short hh = bf16_of(x);
  h = (short)hh;
  l = (short)bf16_of(x - f32_of(hh));
}

// ---------------- Kernel 1: partial Gram G = X^T X via bf16-split MFMA ----------------
// 1024 blocks x 4 waves (4 blocks/CU, 4 waves/SIMD for latency hiding). Each wave
// accumulates a 64x64 G-partial over its 32-row chunks; the 4 waves of a block are
// summed in LDS so only ONE partial per block goes to global (16 MB total).
__global__ __launch_bounds__(256) void k_gram(const float* __restrict__ X,
                                              float* __restrict__ partials,
                                              int N, int cpw) {
  __shared__ float red[2][4096];
  const int t = threadIdx.x;
  const int lane = t & 63;
  const int wave = t >> 6;
  const int gw = blockIdx.x * 4 + wave;     // 0..4095
  const int col = lane & 15;
  const int kg = lane >> 4;                 // k = kg*8 + e

  f32x4 acc[16];
#pragma unroll
  for (int i = 0; i < 16; ++i) acc[i] = (f32x4){0.f, 0.f, 0.f, 0.f};

  for (int c = 0; c < cpw; ++c) {
    long r0 = ((long)gw * cpw + c) * 32;
    if (r0 >= N) break;
    short8 fh[4], fl[4];
#pragma unroll
    for (int b = 0; b < 4; ++b) {
      const float* p = X + (r0 + kg * 8) * MDIM + b * 16 + col;
#pragma unroll
      for (int e = 0; e < 8; ++e) {
        long r = r0 + kg * 8 + e;
        float x = (r < N) ? p[e * MDIM] : 0.f;   // 4x 256B coalesced segments / instr
        short h, l;
        split2(x, h, l);
        fh[b][e] = h;
        fl[b][e] = l;
      }
    }
#pragma unroll
    for (int bi = 0; bi < 4; ++bi)
#pragma unroll
      for (int bj = 0; bj < 4; ++bj) {
        int idx = bi * 4 + bj;
        acc[idx] = __builtin_amdgcn_mfma_f32_16x16x32_bf16(fh[bi], fh[bj], acc[idx], 0, 0, 0);
        acc[idx] = __builtin_amdgcn_mfma_f32_16x16x32_bf16(fh[bi], fl[bj], acc[idx], 0, 0, 0);
        acc[idx] = __builtin_amdgcn_mfma_f32_16x16x32_bf16(fl[bi], fh[bj], acc[idx], 0, 0, 0);
      }
  }

  // C/D layout: col = lane&15, row = (lane>>4)*4 + reg
  // cross-wave reduce in LDS: waves 0,1 write; waves 2,3 add; then 0+1 merged.
  if (wave < 2) {
#pragma unroll
    for (int bi = 0; bi < 4; ++bi)
#pragma unroll
      for (int bj = 0; bj < 4; ++bj)
#pragma unroll
        for (int q = 0; q < 4; ++q)
          red[wave][(bi * 16 + kg * 4 + q) * MDIM + bj * 16 + col] = acc[bi * 4 + bj][q];
  }
  __syncthreads();
  if (wave >= 2) {
    float* dst = red[wave - 2];
#pragma unroll
    for (int bi = 0; bi < 4; ++bi)
#pragma unroll
      for (int bj = 0; bj < 4; ++bj)
#pragma unroll
        for (int q = 0; q < 4; ++q)
          dst[(bi * 16 + kg * 4 + q) * MDIM + bj * 16 + col] += acc[bi * 4 + bj][q];
  }
  __syncthreads();
  float* p = partials + (long)blockIdx.x * 4096;
  for (int e = t; e < 4096; e += 256) p[e] = red[0][e] + red[1][e];
}

// ---------------- Kernel 2a/2b: two-stage reduce of partials -> G ----------------
__global__ __launch_bounds__(256) void k_reduce1(const float* __restrict__ partials,
                                                 float* __restrict__ P2, int nblk) {
  int g = blockIdx.x * 256 + threadIdx.x;  // 0..65535
  int e = g & 4095, s = g >> 12;           // 16 slices
  int p0 = (nblk * s) >> 4, p1 = (nblk * (s + 1)) >> 4;
  float sum = 0.f;
  for (int p = p0; p < p1; ++p) sum += partials[(long)p * 4096 + e];
  P2[g] = sum;
}

__global__ __launch_bounds__(256) void k_reduce2(const float* __restrict__ P2,
                                                 float* __restrict__ G) {
  int e = blockIdx.x * 256 + threadIdx.x;  // grid 16
  float sum = 0.f;
#pragma unroll
  for (int s = 0; s < 16; ++s) sum += P2[s * 4096 + e];
  G[e] = sum;
}

// ---------------- Kernel 3: Cholesky + triangular inverse, LDS-broadcast ----------
// 1 wave. Lane t holds row t of A in regs (static indexing via full unroll).
// Column broadcasts via LDS colbuf (uniform-address ds_read = broadcast, no
// bpermute, no spills). L lands in LDS for the substitution phase.
__global__ __launch_bounds__(64) void k_cholinv(const float* __restrict__ G,
                                                unsigned short* __restrict__ Rh,
                                                unsigned short* __restrict__ Rl) {
  __shared__ float Ls[64][65];   // pad 65: column writes are 2-way (free)
  __shared__ float colbuf[64];
  __shared__ float invd[64];
  const int t = threadIdx.x;

  {
    float row[64];
#pragma unroll
    for (int j4 = 0; j4 < 16; ++j4)
      *reinterpret_cast<f32x4*>(&row[j4 * 4]) =
          *reinterpret_cast<const f32x4*>(G + t * MDIM + j4 * 4);

#pragma unroll
    for (int k = 0; k < 64; ++k) {
      colbuf[t] = row[k];          // column k (valid for lanes >= k)
      __syncthreads();
      float inv = 1.f / sqrtf(colbuf[k]);    // uniform
      if (t == 0) invd[k] = inv;
      float lk = row[k] * inv;               // L[t][k]
      row[k] = lk;
      Ls[t][k] = lk;
#pragma unroll
      for (int j = k + 1; j < 64; ++j)
        row[j] = fmaf(-lk, colbuf[j] * inv, row[j]);   // A[t][j] -= L[t][k]*L[j][k]
      __syncthreads();             // colbuf reused next iter
    }
  }

  // Lane t: column t of Linv. y[i<t]=0 self-masks the uniform loop.
  float y[64];
#pragma unroll
  for (int i = 0; i < 64; ++i) {
    float s = 0.f;
#pragma unroll
    for (int m = 0; m < i; ++m) s = fmaf(Ls[i][m], y[m], s);  // broadcast reads
    y[i] = (i == t) ? invd[i] : -invd[i] * s;
  }

  // Rinv[t][j] = Linv[j][t] = y[j]  (already 0 for j<t); emit bf16 hi/lo
#pragma unroll
  for (int j = 0; j < 64; ++j) {
    float v = y[j];
    unsigned short h = bf16_of(v);
    Rh[t * MDIM + j] = h;
    Rl[t * MDIM + j] = bf16_of(v - f32_of(h));
  }
}

// ---------------- Kernel 4: Q = X * Rinv via bf16-split MFMA -----------------------
// 4 waves/block; wave owns 16 contiguous 16-row tiles. Rinv hi/lo fragments hoisted
// into registers once per wave; X rows read once (float4); Q written coalesced.
__global__ __launch_bounds__(256) void k_apply(const float* __restrict__ X,
                                               const unsigned short* __restrict__ Rh,
                                               const unsigned short* __restrict__ Rl,
                                               float* __restrict__ Q, int N) {
  const int t = threadIdx.x;
  const int lane = t & 63;
  const int wave = t >> 6;
  const int col = lane & 15;
  const int kg = lane >> 4;

  // B-frags: B[k][j], j = jb*16+col, k = kc*32 + kg*8 + e
  short8 bh[4][2], bl[4][2];
#pragma unroll
  for (int jb = 0; jb < 4; ++jb)
#pragma unroll
    for (int kc = 0; kc < 2; ++kc)
#pragma unroll
      for (int e = 0; e < 8; ++e) {
        int k = kc * 32 + kg * 8 + e;
        bh[jb][kc][e] = (short)Rh[k * MDIM + jb * 16 + col];
        bl[jb][kc][e] = (short)Rl[k * MDIM + jb * 16 + col];
      }

  long base = ((long)blockIdx.x * 4 + wave) * 256;   // 16 tiles x 16 rows
#pragma unroll 1
  for (int i = 0; i < 16; ++i) {
    long r0 = base + i * 16;
    if (r0 >= N) break;
    long rr = r0 + col;
    if (rr > N - 1) rr = N - 1;
    const float* xp = X + rr * MDIM + kg * 8;

    short8 ah[2], al[2];
#pragma unroll
    for (int kc = 0; kc < 2; ++kc) {
      float xv[8];
      *reinterpret_cast<f32x4*>(&xv[0]) = *reinterpret_cast<const f32x4*>(xp + kc * 32);
      *reinterpret_cast<f32x4*>(&xv[4]) = *reinterpret_cast<const f32x4*>(xp + kc * 32 + 4);
#pragma unroll
      for (int e = 0; e < 8; ++e) {
        short h, l;
        split2(xv[e], h, l);
        ah[kc][e] = h;
        al[kc][e] = l;
      }
    }

    f32x4 q[4];
#pragma unroll
    for (int jb = 0; jb < 4; ++jb) q[jb] = (f32x4){0.f, 0.f, 0.f, 0.f};
#pragma unroll
    for (int jb = 0; jb < 4; ++jb)
#pragma unroll
      for (int kc = 0; kc < 2; ++kc) {
        q[jb] = __builtin_amdgcn_mfma_f32_16x16x32_bf16(ah[kc], bh[jb][kc], q[jb], 0, 0, 0);
        q[jb] = __builtin_amdgcn_mfma_f32_16x16x32_bf16(ah[kc], bl[jb][kc], q[jb], 0, 0, 0);
        q[jb] = __builtin_amdgcn_mfma_f32_16x16x32_bf16(al[kc], bh[jb][kc], q[jb], 0, 0, 0);
      }

    // C/D: col = lane&15, row = kg*4 + reg
#pragma unroll
    for (int jb = 0; jb < 4; ++jb)
#pragma unroll
      for (int qq = 0; qq < 4; ++qq) {
        long orow = r0 + kg * 4 + qq;
        if (orow < N) Q[orow * MDIM + jb * 16 + col] = q[jb][qq];
      }
  }
}

extern "C" void kernel_launch(void* const* d_in, const int* in_sizes, int n_in,
                              void* d_out, int out_size, void* d_ws, size_t ws_size,
                              hipStream_t stream) {
  const float* X = (const float*)d_in[0];
  float* Q = (float*)d_out;
  const int N = in_sizes[0] / MDIM;

  float* ws = (float*)d_ws;
  float* G = ws;                                   // 4096 f32
  float* P2 = ws + 4096;                           // 65536 f32
  unsigned short* Rh = (unsigned short*)(ws + 69632);  // 4096 bf16
  unsigned short* Rl = (unsigned short*)(ws + 71680);  // 4096 bf16
  float* partials = ws + 73728;                    // 1024 * 4096 f32 (16 MB)

  const int nwave = 4096;                          // 1024 blocks x 4 waves
  int chunks = (N + 31) / 32;
  int cpw = (chunks + nwave - 1) / nwave;

  k_gram<<<1024, 256, 0, stream>>>(X, partials, N, cpw);
  k_reduce1<<<256, 256, 0, stream>>>(partials, P2, 1024);
  k_reduce2<<<16, 256, 0, stream>>>(P2, G);
  k_cholinv<<<1, 64, 0, stream>>>(G, Rh, Rl);
  k_apply<<<(int)((N + 1023) / 1024), 256, 0, stream>>>(X, Rh, Rl, Q, N);
}